// Round 22
// baseline (238.355 us; speedup 1.0000x reference)
//
#include <hip/hip_runtime.h>

#define NN   100000
#define NE   1600000
#define IND  256
#define HIDD 128
#define BCAP 64      // per-node bucket capacity (max in-degree ~40 for this input)
#define NPART 782    // dst>>7 windows of 128 nodes (782*128 = 100096 >= NN)
#define SCAP 2500    // stream capacity: mean 2046 + ~10 sigma
#define APITCH 40    // A staging row pitch in bf16 (32+8): 80 B, 16B-aligned
#define HPITCH 136   // h-tile row pitch (128+8): 272 B, 16B-aligned

typedef __attribute__((ext_vector_type(8))) short short8v;
typedef __attribute__((ext_vector_type(4))) float f32x4;

// ---------------- bf16 helpers ----------------------------------------------
__device__ inline unsigned packbf2(float x, float y) {   // RNE round both
  unsigned xb = __float_as_uint(x);
  unsigned yb = __float_as_uint(y);
  xb += 0x7fffu + ((xb >> 16) & 1u);
  yb += 0x7fffu + ((yb >> 16) & 1u);
  return (xb >> 16) | (yb & 0xffff0000u);
}
__device__ inline unsigned short bf16r(float x) {        // RNE round one
  unsigned b = __float_as_uint(x);
  b += 0x7fffu + ((b >> 16) & 1u);
  return (unsigned short)(b >> 16);
}

// ---------------- weights fp32 -> bf16 (one tiny launch) ----------------------
__global__ void wcvt_all(const float* __restrict__ W1, const float* __restrict__ W2,
                         const float* __restrict__ W3, unsigned* __restrict__ W1b,
                         unsigned* __restrict__ W2b, unsigned* __restrict__ W3b) {
  int i = blockIdx.x * 256 + threadIdx.x;   // 0..32767 u32 slots
  const float* src; unsigned* dst; int off;
  if (i < 16384)      { src = W1; dst = W1b; off = i; }
  else if (i < 24576) { src = W2; dst = W2b; off = i - 16384; }
  else                { src = W3; dst = W3b; off = i - 24576; }
  float2 v = ((const float2*)src)[off];
  dst[off] = packbf2(v.x, v.y);
}

// ---------------- fill phase A: radix partition into 782 streams --------------
// Per-block LDS histogram -> span reservations (612K global atomics total, on
// 782 spread counters) -> dense block-private span writes (write-combined).
// Entry = (dst&127)<<17 | src (24 bits). Replaces direct atomic+scatter
// (r6-r18: pinned ~12.6 Gedge/s by 1.6M cross-XCD cursor RMWs + line-granular
// scatter).
__global__ __launch_bounds__(256, 8) void fill_phaseA(
    const int* __restrict__ src, const int* __restrict__ dst,
    int* __restrict__ gcur, unsigned* __restrict__ sbuf)
{
  __shared__ int hist[NPART];
  __shared__ int lofs[NPART];
  const int tid = threadIdx.x;
  const int base = blockIdx.x * 2048;
  for (int i = tid; i < NPART; i += 256) hist[i] = 0;
  __syncthreads();
  int d[8], s[8];
#pragma unroll
  for (int i = 0; i < 8; ++i) {
    int e = base + i * 256 + tid;
    bool v = e < NE;
    d[i] = v ? dst[e] : -1;
    s[i] = v ? src[e] : 0;
    if (v) atomicAdd(&hist[d[i] >> 7], 1);
  }
  __syncthreads();
  for (int i = tid; i < NPART; i += 256)
    lofs[i] = hist[i] ? atomicAdd(&gcur[i], hist[i]) : 0;   // span reservation
  __syncthreads();
#pragma unroll
  for (int i = 0; i < 8; ++i) {
    if (d[i] >= 0) {
      int p = d[i] >> 7;
      int q = atomicAdd(&lofs[p], 1);           // LDS: offset within stream
      if (q < SCAP)
        sbuf[(size_t)p * SCAP + q] = ((unsigned)(d[i] & 127) << 17) | (unsigned)s[i];
    }
  }
}

// ---------------- fill phase B: per-window scatter with LDS cursors -----------
// One block per 128-node window (782 blocks, ~3/CU — was 196/0.77 in r19-21):
// cursors in LDS (ZERO global atomics), colbuk writes land in a 32KB window
// owned by THIS block only -> single-writer lines, flush once. deg + dinv
// written coalesced (dinv folded here; prep kernel deleted).
__global__ __launch_bounds__(256, 8) void fill_phaseB(
    const unsigned* __restrict__ sbuf, const int* __restrict__ gcur,
    int* __restrict__ colbuk, int* __restrict__ deg, float* __restrict__ dinv)
{
  __shared__ int lcur[128];
  const int tid = threadIdx.x;
  const int b = blockIdx.x;
  if (tid < 128) lcur[tid] = 0;
  __syncthreads();
  int cnt = min(gcur[b], SCAP);
  const unsigned* sp = sbuf + (size_t)b * SCAP;
  for (int i = tid; i < cnt; i += 256) {
    unsigned u = sp[i];
    int dloc = (int)(u >> 17);
    int s = (int)(u & 0x1FFFFu);
    int pos = atomicAdd(&lcur[dloc], 1);
    if (pos < BCAP) colbuk[(size_t)((b << 7) + dloc) * BCAP + pos] = s;
  }
  __syncthreads();
  if (tid < 128) {
    int node = (b << 7) + tid;
    if (node < NN) {
      int dg = lcur[tid];
      deg[node] = dg;                           // true in-degree (uncapped)
      dinv[node] = rsqrtf((float)(dg + 1));     // +1 self-loop
    }
  }
}

// ---------------- fused encoder: x -> h1 -> h2 -> h0 -> z, va -----------------
// r20 (A+B staged): 85us, barrier-bound. r21 (A+B direct): 100us — A-direct
// exposed x-load latency to the MFMA (no staging pipeline). Hybrid: A STAGED
// (LDS, fp32->bf16 in staging, lA aliases hbuf) + B DIRECT from preconverted
// bf16 weights (L2-hot, independent 16B loads) -> half the staging work, no
// lB, LDS 36KB -> 4 blocks/CU. h1/h2 live only in hbuf; epilogue emits z AND
// va = dinv*z (dinv ready — fills run first; prep kernel deleted).
// NOTE (r15): grid.sync() ~140us/barrier on 8-XCD MI355X — never again.
__global__ __launch_bounds__(256) void enc_fused(
    const float* __restrict__ x,
    const unsigned short* __restrict__ W1b, const float* __restrict__ b1,
    const unsigned short* __restrict__ W2b, const float* __restrict__ b2,
    const unsigned short* __restrict__ W3b, const float* __restrict__ b3,
    const float* __restrict__ Wo, const float* __restrict__ dinv,
    float* __restrict__ z, float* __restrict__ va)
{
  __shared__ unsigned short hbuf[128 * HPITCH];   // h-tile; lA aliases it
  __shared__ float zsh[2][128];
  unsigned short* lA = hbuf;                      // phase-1 A staging (10.2KB)
  const int tid = threadIdx.x;
  const int lane = tid & 63, wid = tid >> 6;
  const int wr = wid >> 1, wc = wid & 1;
  const int bm = blockIdx.x * 128;
  const int lr = lane & 15, lg = lane >> 4;

  f32x4 acc[4][4];
#pragma unroll
  for (int i = 0; i < 4; ++i)
#pragma unroll
    for (int j = 0; j < 4; ++j) acc[i][j] = (f32x4){0.f, 0.f, 0.f, 0.f};

  // ---- phase 1: h1 = relu(x @ W1^T + b1); A staged (fp32->bf16), B direct --
  for (int k0 = 0; k0 < IND; k0 += 32) {
#pragma unroll
    for (int s0 = 0; s0 < 512; s0 += 256) {
      int s = s0 + tid, rr = s >> 2, g = s & 3;
      int grow = bm + rr;
      float4 v0 = make_float4(0.f, 0.f, 0.f, 0.f), v1 = v0;
      if (grow < NN) {
        const float* ap = x + (size_t)grow * IND + k0 + g * 8;
        v0 = ((const float4*)ap)[0]; v1 = ((const float4*)ap)[1];
      }
      uint4 pk;
      pk.x = packbf2(v0.x, v0.y); pk.y = packbf2(v0.z, v0.w);
      pk.z = packbf2(v1.x, v1.y); pk.w = packbf2(v1.z, v1.w);
      *(uint4*)&lA[rr * APITCH + g * 8] = pk;
    }
    __syncthreads();
    {
      short8v a[4], b[4];
#pragma unroll
      for (int i = 0; i < 4; ++i)
        a[i] = *(const short8v*)&lA[(wr * 64 + i * 16 + lr) * APITCH + lg * 8];
#pragma unroll
      for (int j = 0; j < 4; ++j)
        b[j] = *(const short8v*)&W1b[(size_t)(wc * 64 + j * 16 + lr) * IND + k0 + lg * 8];
#pragma unroll
      for (int i = 0; i < 4; ++i)
#pragma unroll
        for (int j = 0; j < 4; ++j)
          acc[i][j] = __builtin_amdgcn_mfma_f32_16x16x32_bf16(a[i], b[j], acc[i][j], 0, 0, 0);
    }
    __syncthreads();
  }
  // write h1 -> hbuf (staging dead: all lA reads drained by last barrier)
#pragma unroll
  for (int i = 0; i < 4; ++i)
#pragma unroll
    for (int e = 0; e < 4; ++e) {
      int lrow = wr * 64 + i * 16 + lg * 4 + e;
#pragma unroll
      for (int j = 0; j < 4; ++j) {
        int cc = wc * 64 + j * 16 + lr;
        hbuf[lrow * HPITCH + cc] = bf16r(fmaxf(acc[i][j][e] + b1[cc], 0.f));
      }
    }
  __syncthreads();

  // ---- phase 2: h2 = relu(h1 @ W2^T + b2); A from hbuf, B direct ----
#pragma unroll
  for (int i = 0; i < 4; ++i)
#pragma unroll
    for (int j = 0; j < 4; ++j) acc[i][j] = (f32x4){0.f, 0.f, 0.f, 0.f};
  for (int k0 = 0; k0 < HIDD; k0 += 32) {
    short8v a[4], b[4];
#pragma unroll
    for (int i = 0; i < 4; ++i)
      a[i] = *(const short8v*)&hbuf[(wr * 64 + i * 16 + lr) * HPITCH + k0 + lg * 8];
#pragma unroll
    for (int j = 0; j < 4; ++j)
      b[j] = *(const short8v*)&W2b[(size_t)(wc * 64 + j * 16 + lr) * HIDD + k0 + lg * 8];
#pragma unroll
    for (int i = 0; i < 4; ++i)
#pragma unroll
      for (int j = 0; j < 4; ++j)
        acc[i][j] = __builtin_amdgcn_mfma_f32_16x16x32_bf16(a[i], b[j], acc[i][j], 0, 0, 0);
  }
  __syncthreads();                   // all reads of h1 done before overwrite
#pragma unroll
  for (int i = 0; i < 4; ++i)
#pragma unroll
    for (int e = 0; e < 4; ++e) {
      int lrow = wr * 64 + i * 16 + lg * 4 + e;
#pragma unroll
      for (int j = 0; j < 4; ++j) {
        int cc = wc * 64 + j * 16 + lr;
        hbuf[lrow * HPITCH + cc] = bf16r(fmaxf(acc[i][j][e] + b2[cc], 0.f));
      }
    }
  __syncthreads();

  // ---- phase 3: h0 = relu(h2 @ W3^T + b3) -> z = Wo.h0 (never stored) ----
#pragma unroll
  for (int i = 0; i < 4; ++i)
#pragma unroll
    for (int j = 0; j < 4; ++j) acc[i][j] = (f32x4){0.f, 0.f, 0.f, 0.f};
  for (int k0 = 0; k0 < HIDD; k0 += 32) {
    short8v a[4], b[4];
#pragma unroll
    for (int i = 0; i < 4; ++i)
      a[i] = *(const short8v*)&hbuf[(wr * 64 + i * 16 + lr) * HPITCH + k0 + lg * 8];
#pragma unroll
    for (int j = 0; j < 4; ++j)
      b[j] = *(const short8v*)&W3b[(size_t)(wc * 64 + j * 16 + lr) * HIDD + k0 + lg * 8];
#pragma unroll
    for (int i = 0; i < 4; ++i)
#pragma unroll
      for (int j = 0; j < 4; ++j)
        acc[i][j] = __builtin_amdgcn_mfma_f32_16x16x32_bf16(a[i], b[j], acc[i][j], 0, 0, 0);
  }
  // z epilogue (r13-verified): z[row] = sum_cc Wo[cc]*relu(acc+b3[cc])
  float wv[4];
#pragma unroll
  for (int j = 0; j < 4; ++j) wv[j] = Wo[wc * 64 + j * 16 + lr];
  zsh[tid >> 7][tid & 127] = 0.f;
  __syncthreads();
#pragma unroll
  for (int i = 0; i < 4; ++i)
#pragma unroll
    for (int e = 0; e < 4; ++e) {
      float part = 0.f;
#pragma unroll
      for (int j = 0; j < 4; ++j) {
        int cc = wc * 64 + j * 16 + lr;
        part += fmaxf(acc[i][j][e] + b3[cc], 0.f) * wv[j];
      }
#pragma unroll
      for (int off = 8; off > 0; off >>= 1) part += __shfl_down(part, off, 16);
      if (lr == 0) zsh[wc][wr * 64 + i * 16 + lg * 4 + e] = part;
    }
  __syncthreads();
  if (tid < 128) {
    int row = bm + tid;
    if (row < NN) {
      float zv = zsh[0][tid] + zsh[1][tid];
      z[row] = zv;
      va[row] = dinv[row] * zv;                 // v0 folded in (prep deleted)
    }
  }
}

// ---------------- scalar APPNP step ------------------------------------------
// Propagation commutes with the Wo projection (A acts on nodes, Wo on
// features; ReLU is encoder-only) -> all 10 steps run on per-node scalars.
// s' = 0.9*dinv*(sum_nbr v + v_self) + 0.1*z ; v' = dinv*s'. v = 400KB L2-hot.
// 16 lanes/node (avg deg ~16, max ~40 -> <=3 gather iters), width-16 reduce.
template<int LAST>
__global__ __launch_bounds__(256, 8) void appnp_sstep(
    const float* __restrict__ vin, const float* __restrict__ z,
    const float* __restrict__ dinv, const int* __restrict__ deg,
    const int* __restrict__ colbuk, float* __restrict__ vout,
    const float* __restrict__ bo, float* __restrict__ out)
{
  int tid = threadIdx.x;
  int sl = tid & 15;
  int node = blockIdx.x * 16 + (tid >> 4);
  if (node >= NN) return;
  int m = min(deg[node], BCAP);
  float val = (sl == 0) ? vin[node] : 0.f;        // self-loop term
  for (int j = sl; j < m; j += 16)
    val += vin[colbuk[(size_t)node * BCAP + j]];
#pragma unroll
  for (int off = 8; off > 0; off >>= 1) val += __shfl_down(val, off, 16);
  if (sl == 0) {
    float di = dinv[node];
    float s = 0.9f * di * val + 0.1f * z[node];
    if (LAST) out[node] = s + bo[0];
    else vout[node] = di * s;
  }
}

// ---------------- launch -----------------------------------------------------
extern "C" void kernel_launch(void* const* d_in, const int* in_sizes, int n_in,
                              void* d_out, int out_size, void* d_ws, size_t ws_size,
                              hipStream_t stream) {
  const float* x   = (const float*)d_in[0];
  const int*   ei  = (const int*)d_in[1];     // [2, NE] flat: src then dst
  const float* W1  = (const float*)d_in[2];
  const float* b1  = (const float*)d_in[3];
  const float* W2  = (const float*)d_in[4];
  const float* b2  = (const float*)d_in[5];
  const float* W3  = (const float*)d_in[6];
  const float* b3  = (const float*)d_in[7];
  const float* Wo  = (const float*)d_in[8];
  const float* bo  = (const float*)d_in[9];
  float* out = (float*)d_out;

  const int* srcv = ei;
  const int* dstv = ei + NE;

  // workspace layout
  int*      colbuk = (int*)d_ws;                              // NN*BCAP
  unsigned* sbuf   = (unsigned*)(colbuk + (size_t)NN * BCAP); // NPART*SCAP
  int*      gcur   = (int*)(sbuf + (size_t)NPART * SCAP);     // NPART
  int*      deg    = gcur + NPART;                            // NN
  float*    dinv   = (float*)(deg + NN);                      // NN
  float*    zbuf   = dinv + NN;                               // NN
  float*    va     = zbuf + NN;                               // NN
  float*    vb     = va + NN;                                 // NN
  unsigned* W1b    = (unsigned*)(vb + NN);                    // 16384 u32
  unsigned* W2b    = W1b + 16384;                             // 8192 u32
  unsigned* W3b    = W2b + 8192;                              // 8192 u32

  hipMemsetAsync(gcur, 0, NPART * 4, stream);

  // weights -> bf16 (for enc_fused's direct B-fragment loads)
  wcvt_all<<<128, 256, 0, stream>>>(W1, W2, W3, W1b, W2b, W3b);

  // graph build: radix partition (A) + LDS-cursor scatter (B; writes dinv too)
  fill_phaseA<<<(NE + 2047) / 2048, 256, 0, stream>>>(srcv, dstv, gcur, sbuf);
  fill_phaseB<<<NPART, 256, 0, stream>>>(sbuf, gcur, colbuk, deg, dinv);

  // fused encoder: x -> (h1 -> h2 -> h0 in LDS) -> z, va
  const int ng = (NN + 127) / 128;            // 782 blocks
  enc_fused<<<ng, 256, 0, stream>>>(x, (unsigned short*)W1b, b1,
                                    (unsigned short*)W2b, b2,
                                    (unsigned short*)W3b, b3, Wo, dinv,
                                    zbuf, va);

  // 10 scalar propagation steps (pure fp32)
  int ssb = (NN + 15) / 16;
  float* cur = va; float* nxt = vb;
  for (int k = 0; k < 9; ++k) {
    appnp_sstep<0><<<ssb, 256, 0, stream>>>(cur, zbuf, dinv, deg, colbuk,
                                            nxt, nullptr, nullptr);
    float* t = cur; cur = nxt; nxt = t;
  }
  appnp_sstep<1><<<ssb, 256, 0, stream>>>(cur, zbuf, dinv, deg, colbuk,
                                          nullptr, bo, out);
}

// Round 23
// 223.781 us; speedup vs baseline: 1.0651x; 1.0651x over previous
//
#include <hip/hip_runtime.h>

#define NN   100000
#define NE   1600000
#define IND  256
#define HIDD 128
#define BCAP 64      // per-node bucket capacity (max in-degree ~40 for this input)
#define NPART 196    // dst>>9 windows of 512 nodes (196*512 >= NN) — r20-proven
#define SCAP 10240   // stream capacity: mean 8163 + 23 sigma
#define APITCH 40    // A staging row pitch in bf16 (32+8): 80 B, 16B-aligned
#define HPITCH 136   // h-tile row pitch (128+8): 272 B, 16B-aligned

typedef __attribute__((ext_vector_type(8))) short short8v;
typedef __attribute__((ext_vector_type(4))) float f32x4;

// ---------------- bf16 helpers ----------------------------------------------
__device__ inline unsigned packbf2(float x, float y) {   // RNE round both
  unsigned xb = __float_as_uint(x);
  unsigned yb = __float_as_uint(y);
  xb += 0x7fffu + ((xb >> 16) & 1u);
  yb += 0x7fffu + ((yb >> 16) & 1u);
  return (xb >> 16) | (yb & 0xffff0000u);
}
__device__ inline unsigned short bf16r(float x) {        // RNE round one
  unsigned b = __float_as_uint(x);
  b += 0x7fffu + ((b >> 16) & 1u);
  return (unsigned short)(b >> 16);
}

// ---------------- weights fp32 -> bf16 (one tiny launch) ----------------------
__global__ void wcvt_all(const float* __restrict__ W1, const float* __restrict__ W2,
                         const float* __restrict__ W3, unsigned* __restrict__ W1b,
                         unsigned* __restrict__ W2b, unsigned* __restrict__ W3b) {
  int i = blockIdx.x * 256 + threadIdx.x;   // 0..32767 u32 slots
  const float* src; unsigned* dst; int off;
  if (i < 16384)      { src = W1; dst = W1b; off = i; }
  else if (i < 24576) { src = W2; dst = W2b; off = i - 16384; }
  else                { src = W3; dst = W3b; off = i - 24576; }
  float2 v = ((const float2*)src)[off];
  dst[off] = packbf2(v.x, v.y);
}

// ---------------- fill phase A: radix partition into 196 streams --------------
// Per-block LDS histogram -> 196 span reservations (153K global atomics TOTAL,
// not 1.6M) -> dense block-private span writes (write-combined). Entry =
// (dst&511)<<17 | src (26 bits). r20-proven config (r22's 782-way cost +22us).
__global__ __launch_bounds__(256, 8) void fill_phaseA(
    const int* __restrict__ src, const int* __restrict__ dst,
    int* __restrict__ gcur, unsigned* __restrict__ sbuf)
{
  __shared__ int hist[NPART];
  __shared__ int lofs[NPART];
  const int tid = threadIdx.x;
  const int base = blockIdx.x * 2048;
  for (int i = tid; i < NPART; i += 256) hist[i] = 0;
  __syncthreads();
  int d[8], s[8];
#pragma unroll
  for (int i = 0; i < 8; ++i) {
    int e = base + i * 256 + tid;
    bool v = e < NE;
    d[i] = v ? dst[e] : -1;
    s[i] = v ? src[e] : 0;
    if (v) atomicAdd(&hist[d[i] >> 9], 1);
  }
  __syncthreads();
  for (int i = tid; i < NPART; i += 256)
    lofs[i] = hist[i] ? atomicAdd(&gcur[i], hist[i]) : 0;   // span reservation
  __syncthreads();
#pragma unroll
  for (int i = 0; i < 8; ++i) {
    if (d[i] >= 0) {
      int p = d[i] >> 9;
      int q = atomicAdd(&lofs[p], 1);           // LDS: offset within stream
      if (q < SCAP)
        sbuf[(size_t)p * SCAP + q] = ((unsigned)(d[i] & 511) << 17) | (unsigned)s[i];
    }
  }
}

// ---------------- fill phase B: per-window scatter with LDS cursors -----------
// One block per 512-node window: cursors in LDS (ZERO global atomics), colbuk
// writes land in a 128KB window owned by THIS block only -> single-writer
// lines, flush once. deg + dinv written coalesced (prep kernel deleted).
__global__ __launch_bounds__(256, 8) void fill_phaseB(
    const unsigned* __restrict__ sbuf, const int* __restrict__ gcur,
    int* __restrict__ colbuk, int* __restrict__ deg, float* __restrict__ dinv)
{
  __shared__ int lcur[512];
  const int tid = threadIdx.x;
  const int b = blockIdx.x;
  for (int i = tid; i < 512; i += 256) lcur[i] = 0;
  __syncthreads();
  int cnt = min(gcur[b], SCAP);
  const unsigned* sp = sbuf + (size_t)b * SCAP;
  for (int i = tid; i < cnt; i += 256) {
    unsigned u = sp[i];
    int dloc = (int)(u >> 17);
    int s = (int)(u & 0x1FFFFu);
    int pos = atomicAdd(&lcur[dloc], 1);
    if (pos < BCAP) colbuk[(size_t)((b << 9) + dloc) * BCAP + pos] = s;
  }
  __syncthreads();
  for (int i = tid; i < 512; i += 256) {
    int node = (b << 9) + i;
    if (node < NN) {
      int dg = lcur[i];
      deg[node] = dg;                           // true in-degree (uncapped)
      dinv[node] = rsqrtf((float)(dg + 1));     // +1 self-loop
    }
  }
}

// ---------------- fused encoder (64-row tiles): x -> h1 -> h2 -> h0 -> z, va --
// r20/r22 at 128-row tiles were residency-starved: 782 blocks, 35KB LDS, 64
// AGPR acc -> occupancy 16.6%, every K-iter's staging latency exposed. Now:
// 64-row tiles -> 1563 blocks, hbuf 17.4KB (8 blocks/CU LDS-cap), wave tile
// 32x64 (acc[2][4] = 32 AGPR) -> 2-4x resident waves to hide latency. A staged
// (fp32->bf16, lA aliases hbuf), B DIRECT from preconverted bf16 weights
// (L2-hot; proven cost-neutral r22 but keeps LDS small). Epilogue emits z AND
// va = dinv*z (fills run first).
// NOTE (r15): grid.sync() ~140us/barrier on 8-XCD MI355X — never again.
__global__ __launch_bounds__(256) void enc_fused(
    const float* __restrict__ x,
    const unsigned short* __restrict__ W1b, const float* __restrict__ b1,
    const unsigned short* __restrict__ W2b, const float* __restrict__ b2,
    const unsigned short* __restrict__ W3b, const float* __restrict__ b3,
    const float* __restrict__ Wo, const float* __restrict__ dinv,
    float* __restrict__ z, float* __restrict__ va)
{
  __shared__ unsigned short hbuf[64 * HPITCH];    // h-tile; lA aliases it
  __shared__ float zsh[2][64];
  unsigned short* lA = hbuf;                      // phase-1 A staging [64][40]
  const int tid = threadIdx.x;
  const int lane = tid & 63, wid = tid >> 6;
  const int wr = wid >> 1, wc = wid & 1;          // wave tile: 32 rows x 64 cols
  const int bm = blockIdx.x * 64;
  const int lr = lane & 15, lg = lane >> 4;

  f32x4 acc[2][4];
#pragma unroll
  for (int i = 0; i < 2; ++i)
#pragma unroll
    for (int j = 0; j < 4; ++j) acc[i][j] = (f32x4){0.f, 0.f, 0.f, 0.f};

  // ---- phase 1: h1 = relu(x @ W1^T + b1); A staged (fp32->bf16), B direct --
  for (int k0 = 0; k0 < IND; k0 += 32) {
    {
      int rr = tid >> 2, g = tid & 3;             // 256 slots = [64][4x8]
      int grow = bm + rr;
      float4 v0 = make_float4(0.f, 0.f, 0.f, 0.f), v1 = v0;
      if (grow < NN) {
        const float* ap = x + (size_t)grow * IND + k0 + g * 8;
        v0 = ((const float4*)ap)[0]; v1 = ((const float4*)ap)[1];
      }
      uint4 pk;
      pk.x = packbf2(v0.x, v0.y); pk.y = packbf2(v0.z, v0.w);
      pk.z = packbf2(v1.x, v1.y); pk.w = packbf2(v1.z, v1.w);
      *(uint4*)&lA[rr * APITCH + g * 8] = pk;
    }
    __syncthreads();
    {
      short8v a[2], b[4];
#pragma unroll
      for (int i = 0; i < 2; ++i)
        a[i] = *(const short8v*)&lA[(wr * 32 + i * 16 + lr) * APITCH + lg * 8];
#pragma unroll
      for (int j = 0; j < 4; ++j)
        b[j] = *(const short8v*)&W1b[(size_t)(wc * 64 + j * 16 + lr) * IND + k0 + lg * 8];
#pragma unroll
      for (int i = 0; i < 2; ++i)
#pragma unroll
        for (int j = 0; j < 4; ++j)
          acc[i][j] = __builtin_amdgcn_mfma_f32_16x16x32_bf16(a[i], b[j], acc[i][j], 0, 0, 0);
    }
    __syncthreads();
  }
  // write h1 -> hbuf (staging dead: all lA reads drained by last barrier)
#pragma unroll
  for (int i = 0; i < 2; ++i)
#pragma unroll
    for (int e = 0; e < 4; ++e) {
      int lrow = wr * 32 + i * 16 + lg * 4 + e;
#pragma unroll
      for (int j = 0; j < 4; ++j) {
        int cc = wc * 64 + j * 16 + lr;
        hbuf[lrow * HPITCH + cc] = bf16r(fmaxf(acc[i][j][e] + b1[cc], 0.f));
      }
    }
  __syncthreads();

  // ---- phase 2: h2 = relu(h1 @ W2^T + b2); A from hbuf, B direct ----
#pragma unroll
  for (int i = 0; i < 2; ++i)
#pragma unroll
    for (int j = 0; j < 4; ++j) acc[i][j] = (f32x4){0.f, 0.f, 0.f, 0.f};
  for (int k0 = 0; k0 < HIDD; k0 += 32) {
    short8v a[2], b[4];
#pragma unroll
    for (int i = 0; i < 2; ++i)
      a[i] = *(const short8v*)&hbuf[(wr * 32 + i * 16 + lr) * HPITCH + k0 + lg * 8];
#pragma unroll
    for (int j = 0; j < 4; ++j)
      b[j] = *(const short8v*)&W2b[(size_t)(wc * 64 + j * 16 + lr) * HIDD + k0 + lg * 8];
#pragma unroll
    for (int i = 0; i < 2; ++i)
#pragma unroll
      for (int j = 0; j < 4; ++j)
        acc[i][j] = __builtin_amdgcn_mfma_f32_16x16x32_bf16(a[i], b[j], acc[i][j], 0, 0, 0);
  }
  __syncthreads();                   // all reads of h1 done before overwrite
#pragma unroll
  for (int i = 0; i < 2; ++i)
#pragma unroll
    for (int e = 0; e < 4; ++e) {
      int lrow = wr * 32 + i * 16 + lg * 4 + e;
#pragma unroll
      for (int j = 0; j < 4; ++j) {
        int cc = wc * 64 + j * 16 + lr;
        hbuf[lrow * HPITCH + cc] = bf16r(fmaxf(acc[i][j][e] + b2[cc], 0.f));
      }
    }
  __syncthreads();

  // ---- phase 3: h0 = relu(h2 @ W3^T + b3) -> z = Wo.h0 (never stored) ----
#pragma unroll
  for (int i = 0; i < 2; ++i)
#pragma unroll
    for (int j = 0; j < 4; ++j) acc[i][j] = (f32x4){0.f, 0.f, 0.f, 0.f};
  for (int k0 = 0; k0 < HIDD; k0 += 32) {
    short8v a[2], b[4];
#pragma unroll
    for (int i = 0; i < 2; ++i)
      a[i] = *(const short8v*)&hbuf[(wr * 32 + i * 16 + lr) * HPITCH + k0 + lg * 8];
#pragma unroll
    for (int j = 0; j < 4; ++j)
      b[j] = *(const short8v*)&W3b[(size_t)(wc * 64 + j * 16 + lr) * HIDD + k0 + lg * 8];
#pragma unroll
    for (int i = 0; i < 2; ++i)
#pragma unroll
      for (int j = 0; j < 4; ++j)
        acc[i][j] = __builtin_amdgcn_mfma_f32_16x16x32_bf16(a[i], b[j], acc[i][j], 0, 0, 0);
  }
  // z epilogue (r13-verified): z[row] = sum_cc Wo[cc]*relu(acc+b3[cc])
  float wv[4];
#pragma unroll
  for (int j = 0; j < 4; ++j) wv[j] = Wo[wc * 64 + j * 16 + lr];
  if (tid < 128) { zsh[tid >> 6][tid & 63] = 0.f; }
  __syncthreads();
#pragma unroll
  for (int i = 0; i < 2; ++i)
#pragma unroll
    for (int e = 0; e < 4; ++e) {
      float part = 0.f;
#pragma unroll
      for (int j = 0; j < 4; ++j) {
        int cc = wc * 64 + j * 16 + lr;
        part += fmaxf(acc[i][j][e] + b3[cc], 0.f) * wv[j];
      }
#pragma unroll
      for (int off = 8; off > 0; off >>= 1) part += __shfl_down(part, off, 16);
      if (lr == 0) zsh[wc][wr * 32 + i * 16 + lg * 4 + e] = part;
    }
  __syncthreads();
  if (tid < 64) {
    int row = bm + tid;
    if (row < NN) {
      float zv = zsh[0][tid] + zsh[1][tid];
      z[row] = zv;
      va[row] = dinv[row] * zv;                 // v0 folded in (prep deleted)
    }
  }
}

// ---------------- scalar APPNP step ------------------------------------------
// Propagation commutes with the Wo projection (A acts on nodes, Wo on
// features; ReLU is encoder-only) -> all 10 steps run on per-node scalars.
// s' = 0.9*dinv*(sum_nbr v + v_self) + 0.1*z ; v' = dinv*s'. v = 400KB L2-hot.
// 16 lanes/node (avg deg ~16, max ~40 -> <=3 gather iters), width-16 reduce.
template<int LAST>
__global__ __launch_bounds__(256, 8) void appnp_sstep(
    const float* __restrict__ vin, const float* __restrict__ z,
    const float* __restrict__ dinv, const int* __restrict__ deg,
    const int* __restrict__ colbuk, float* __restrict__ vout,
    const float* __restrict__ bo, float* __restrict__ out)
{
  int tid = threadIdx.x;
  int sl = tid & 15;
  int node = blockIdx.x * 16 + (tid >> 4);
  if (node >= NN) return;
  int m = min(deg[node], BCAP);
  float val = (sl == 0) ? vin[node] : 0.f;        // self-loop term
  for (int j = sl; j < m; j += 16)
    val += vin[colbuk[(size_t)node * BCAP + j]];
#pragma unroll
  for (int off = 8; off > 0; off >>= 1) val += __shfl_down(val, off, 16);
  if (sl == 0) {
    float di = dinv[node];
    float s = 0.9f * di * val + 0.1f * z[node];
    if (LAST) out[node] = s + bo[0];
    else vout[node] = di * s;
  }
}

// ---------------- launch -----------------------------------------------------
extern "C" void kernel_launch(void* const* d_in, const int* in_sizes, int n_in,
                              void* d_out, int out_size, void* d_ws, size_t ws_size,
                              hipStream_t stream) {
  const float* x   = (const float*)d_in[0];
  const int*   ei  = (const int*)d_in[1];     // [2, NE] flat: src then dst
  const float* W1  = (const float*)d_in[2];
  const float* b1  = (const float*)d_in[3];
  const float* W2  = (const float*)d_in[4];
  const float* b2  = (const float*)d_in[5];
  const float* W3  = (const float*)d_in[6];
  const float* b3  = (const float*)d_in[7];
  const float* Wo  = (const float*)d_in[8];
  const float* bo  = (const float*)d_in[9];
  float* out = (float*)d_out;

  const int* srcv = ei;
  const int* dstv = ei + NE;

  // workspace layout
  int*      colbuk = (int*)d_ws;                              // NN*BCAP
  unsigned* sbuf   = (unsigned*)(colbuk + (size_t)NN * BCAP); // NPART*SCAP
  int*      gcur   = (int*)(sbuf + (size_t)NPART * SCAP);     // NPART
  int*      deg    = gcur + NPART;                            // NN
  float*    dinv   = (float*)(deg + NN);                      // NN
  float*    zbuf   = dinv + NN;                               // NN
  float*    va     = zbuf + NN;                               // NN
  float*    vb     = va + NN;                                 // NN
  unsigned* W1b    = (unsigned*)(vb + NN);                    // 16384 u32
  unsigned* W2b    = W1b + 16384;                             // 8192 u32
  unsigned* W3b    = W2b + 8192;                              // 8192 u32

  hipMemsetAsync(gcur, 0, NPART * 4, stream);

  // weights -> bf16 (for enc_fused's direct B-fragment loads)
  wcvt_all<<<128, 256, 0, stream>>>(W1, W2, W3, W1b, W2b, W3b);

  // graph build: radix partition (A) + LDS-cursor scatter (B; writes dinv too)
  fill_phaseA<<<(NE + 2047) / 2048, 256, 0, stream>>>(srcv, dstv, gcur, sbuf);
  fill_phaseB<<<NPART, 256, 0, stream>>>(sbuf, gcur, colbuk, deg, dinv);

  // fused encoder: x -> (h1 -> h2 -> h0 in LDS) -> z, va   (64-row tiles)
  const int ng = (NN + 63) / 64;              // 1563 blocks
  enc_fused<<<ng, 256, 0, stream>>>(x, (unsigned short*)W1b, b1,
                                    (unsigned short*)W2b, b2,
                                    (unsigned short*)W3b, b3, Wo, dinv,
                                    zbuf, va);

  // 10 scalar propagation steps (pure fp32)
  int ssb = (NN + 15) / 16;
  float* cur = va; float* nxt = vb;
  for (int k = 0; k < 9; ++k) {
    appnp_sstep<0><<<ssb, 256, 0, stream>>>(cur, zbuf, dinv, deg, colbuk,
                                            nxt, nullptr, nullptr);
    float* t = cur; cur = nxt; nxt = t;
  }
  appnp_sstep<1><<<ssb, 256, 0, stream>>>(cur, zbuf, dinv, deg, colbuk,
                                          nullptr, bo, out);
}

// Round 24
// 207.640 us; speedup vs baseline: 1.1479x; 1.0777x over previous
//
#include <hip/hip_runtime.h>

#define NN   100000
#define NE   1600000
#define IND  256
#define HIDD 128
#define BCAP 64      // per-node bucket capacity (max in-degree ~40 for this input)
#define NPART 196    // dst>>9 windows of 512 nodes (196*512 >= NN) — r20-proven
#define SCAP 10240   // stream capacity: mean 8163 + 23 sigma
#define APITCH 40    // A staging row pitch in bf16 (32+8): 80 B, 16B-aligned
#define HPITCH 136   // h-tile row pitch (128+8): 272 B, 16B-aligned
#define NGE  1563    // enc gemm blocks (64-row tiles)
#define NFA  782     // fillA blocks (2048 edges each)

typedef __attribute__((ext_vector_type(8))) short short8v;
typedef __attribute__((ext_vector_type(4))) float f32x4;

// ---------------- bf16 helpers ----------------------------------------------
__device__ inline unsigned packbf2(float x, float y) {   // RNE round both
  unsigned xb = __float_as_uint(x);
  unsigned yb = __float_as_uint(y);
  xb += 0x7fffu + ((xb >> 16) & 1u);
  yb += 0x7fffu + ((yb >> 16) & 1u);
  return (xb >> 16) | (yb & 0xffff0000u);
}
__device__ inline unsigned short bf16r(float x) {        // RNE round one
  unsigned b = __float_as_uint(x);
  b += 0x7fffu + ((b >> 16) & 1u);
  return (unsigned short)(b >> 16);
}

// ---------------- weights fp32 -> bf16 (one tiny launch) ----------------------
__global__ void wcvt_all(const float* __restrict__ W1, const float* __restrict__ W2,
                         const float* __restrict__ W3, unsigned* __restrict__ W1b,
                         unsigned* __restrict__ W2b, unsigned* __restrict__ W3b) {
  int i = blockIdx.x * 256 + threadIdx.x;   // 0..32767 u32 slots
  const float* src; unsigned* dst; int off;
  if (i < 16384)      { src = W1; dst = W1b; off = i; }
  else if (i < 24576) { src = W2; dst = W2b; off = i - 16384; }
  else                { src = W3; dst = W3b; off = i - 24576; }
  float2 v = ((const float2*)src)[off];
  dst[off] = packbf2(v.x, v.y);
}

// ---------------- fused: encoder (64-row tiles) | fillA radix blocks ----------
// enc is latency/barrier-bound at ~84us with ALL pipes idle (r20-r23: MfmaUtil
// 6%, HBM 8%, VALU 12%, invariant across staged/direct/64-row variants). So
// stripe fillA's 782 blocks into the enc grid 1:2 (grid 2346): fillA's
// histogram+stream-write traffic runs in enc's shadow. Unlike r8/r17 failures:
// host LDS is small (~20KB -> fill blocks keep 8-blk/CU residency) and host is
// latency-bound, not compute-busy.
// enc: x -> h1 -> h2 -> h0 (all in hbuf) -> z. A staged (fp32->bf16, lA
// aliases hbuf), B direct from preconverted bf16 weights (L2-hot).
// fillA: per-block LDS histogram -> 196 span reservations (153K atomics total)
// -> dense block-private span writes. Entry = (dst&511)<<17 | src.
// NOTE (r15): grid.sync() ~140us/barrier on 8-XCD MI355X — never again.
__global__ __launch_bounds__(256) void enc_fillA(
    const float* __restrict__ x,
    const unsigned short* __restrict__ W1b, const float* __restrict__ b1,
    const unsigned short* __restrict__ W2b, const float* __restrict__ b2,
    const unsigned short* __restrict__ W3b, const float* __restrict__ b3,
    const float* __restrict__ Wo, float* __restrict__ z,
    const int* __restrict__ src, const int* __restrict__ dst,
    int* __restrict__ gcur, unsigned* __restrict__ sbuf)
{
  __shared__ unsigned short hbuf[64 * HPITCH];    // h-tile; lA aliases it
  __shared__ float zsh[2][64];
  __shared__ int hist[NPART];
  __shared__ int lofs[NPART];
  const int tid = threadIdx.x;
  const int bid = blockIdx.x;
  const int r3v = bid % 3;

  if (r3v == 2) {                        // ---- fillA block (fi = 0..781) ----
    int fi = bid / 3;
    const int base = fi * 2048;
    for (int i = tid; i < NPART; i += 256) hist[i] = 0;
    __syncthreads();
    int d[8], s[8];
#pragma unroll
    for (int i = 0; i < 8; ++i) {
      int e = base + i * 256 + tid;
      bool v = e < NE;
      d[i] = v ? dst[e] : -1;
      s[i] = v ? src[e] : 0;
      if (v) atomicAdd(&hist[d[i] >> 9], 1);
    }
    __syncthreads();
    for (int i = tid; i < NPART; i += 256)
      lofs[i] = hist[i] ? atomicAdd(&gcur[i], hist[i]) : 0;   // span reserve
    __syncthreads();
#pragma unroll
    for (int i = 0; i < 8; ++i) {
      if (d[i] >= 0) {
        int p = d[i] >> 9;
        int q = atomicAdd(&lofs[p], 1);           // LDS: offset within stream
        if (q < SCAP)
          sbuf[(size_t)p * SCAP + q] = ((unsigned)(d[i] & 511) << 17) | (unsigned)s[i];
      }
    }
    return;
  }

  const int gb = (bid / 3) * 2 + r3v;
  if (gb >= NGE) return;
  unsigned short* lA = hbuf;                      // phase-1 A staging [64][40]
  const int lane = tid & 63, wid = tid >> 6;
  const int wr = wid >> 1, wc = wid & 1;          // wave tile: 32 rows x 64 cols
  const int bm = gb * 64;
  const int lr = lane & 15, lg = lane >> 4;

  f32x4 acc[2][4];
#pragma unroll
  for (int i = 0; i < 2; ++i)
#pragma unroll
    for (int j = 0; j < 4; ++j) acc[i][j] = (f32x4){0.f, 0.f, 0.f, 0.f};

  // ---- phase 1: h1 = relu(x @ W1^T + b1); A staged (fp32->bf16), B direct --
  for (int k0 = 0; k0 < IND; k0 += 32) {
    {
      int rr = tid >> 2, g = tid & 3;             // 256 slots = [64][4x8]
      int grow = bm + rr;
      float4 v0 = make_float4(0.f, 0.f, 0.f, 0.f), v1 = v0;
      if (grow < NN) {
        const float* ap = x + (size_t)grow * IND + k0 + g * 8;
        v0 = ((const float4*)ap)[0]; v1 = ((const float4*)ap)[1];
      }
      uint4 pk;
      pk.x = packbf2(v0.x, v0.y); pk.y = packbf2(v0.z, v0.w);
      pk.z = packbf2(v1.x, v1.y); pk.w = packbf2(v1.z, v1.w);
      *(uint4*)&lA[rr * APITCH + g * 8] = pk;
    }
    __syncthreads();
    {
      short8v a[2], b[4];
#pragma unroll
      for (int i = 0; i < 2; ++i)
        a[i] = *(const short8v*)&lA[(wr * 32 + i * 16 + lr) * APITCH + lg * 8];
#pragma unroll
      for (int j = 0; j < 4; ++j)
        b[j] = *(const short8v*)&W1b[(size_t)(wc * 64 + j * 16 + lr) * IND + k0 + lg * 8];
#pragma unroll
      for (int i = 0; i < 2; ++i)
#pragma unroll
        for (int j = 0; j < 4; ++j)
          acc[i][j] = __builtin_amdgcn_mfma_f32_16x16x32_bf16(a[i], b[j], acc[i][j], 0, 0, 0);
    }
    __syncthreads();
  }
  // write h1 -> hbuf (staging dead: all lA reads drained by last barrier)
#pragma unroll
  for (int i = 0; i < 2; ++i)
#pragma unroll
    for (int e = 0; e < 4; ++e) {
      int lrow = wr * 32 + i * 16 + lg * 4 + e;
#pragma unroll
      for (int j = 0; j < 4; ++j) {
        int cc = wc * 64 + j * 16 + lr;
        hbuf[lrow * HPITCH + cc] = bf16r(fmaxf(acc[i][j][e] + b1[cc], 0.f));
      }
    }
  __syncthreads();

  // ---- phase 2: h2 = relu(h1 @ W2^T + b2); A from hbuf, B direct ----
#pragma unroll
  for (int i = 0; i < 2; ++i)
#pragma unroll
    for (int j = 0; j < 4; ++j) acc[i][j] = (f32x4){0.f, 0.f, 0.f, 0.f};
  for (int k0 = 0; k0 < HIDD; k0 += 32) {
    short8v a[2], b[4];
#pragma unroll
    for (int i = 0; i < 2; ++i)
      a[i] = *(const short8v*)&hbuf[(wr * 32 + i * 16 + lr) * HPITCH + k0 + lg * 8];
#pragma unroll
    for (int j = 0; j < 4; ++j)
      b[j] = *(const short8v*)&W2b[(size_t)(wc * 64 + j * 16 + lr) * HIDD + k0 + lg * 8];
#pragma unroll
    for (int i = 0; i < 2; ++i)
#pragma unroll
      for (int j = 0; j < 4; ++j)
        acc[i][j] = __builtin_amdgcn_mfma_f32_16x16x32_bf16(a[i], b[j], acc[i][j], 0, 0, 0);
  }
  __syncthreads();                   // all reads of h1 done before overwrite
#pragma unroll
  for (int i = 0; i < 2; ++i)
#pragma unroll
    for (int e = 0; e < 4; ++e) {
      int lrow = wr * 32 + i * 16 + lg * 4 + e;
#pragma unroll
      for (int j = 0; j < 4; ++j) {
        int cc = wc * 64 + j * 16 + lr;
        hbuf[lrow * HPITCH + cc] = bf16r(fmaxf(acc[i][j][e] + b2[cc], 0.f));
      }
    }
  __syncthreads();

  // ---- phase 3: h0 = relu(h2 @ W3^T + b3) -> z = Wo.h0 (never stored) ----
#pragma unroll
  for (int i = 0; i < 2; ++i)
#pragma unroll
    for (int j = 0; j < 4; ++j) acc[i][j] = (f32x4){0.f, 0.f, 0.f, 0.f};
  for (int k0 = 0; k0 < HIDD; k0 += 32) {
    short8v a[2], b[4];
#pragma unroll
    for (int i = 0; i < 2; ++i)
      a[i] = *(const short8v*)&hbuf[(wr * 32 + i * 16 + lr) * HPITCH + k0 + lg * 8];
#pragma unroll
    for (int j = 0; j < 4; ++j)
      b[j] = *(const short8v*)&W3b[(size_t)(wc * 64 + j * 16 + lr) * HIDD + k0 + lg * 8];
#pragma unroll
    for (int i = 0; i < 2; ++i)
#pragma unroll
      for (int j = 0; j < 4; ++j)
        acc[i][j] = __builtin_amdgcn_mfma_f32_16x16x32_bf16(a[i], b[j], acc[i][j], 0, 0, 0);
  }
  // z epilogue (r13-verified): z[row] = sum_cc Wo[cc]*relu(acc+b3[cc])
  float wv[4];
#pragma unroll
  for (int j = 0; j < 4; ++j) wv[j] = Wo[wc * 64 + j * 16 + lr];
  if (tid < 128) { zsh[tid >> 6][tid & 63] = 0.f; }
  __syncthreads();
#pragma unroll
  for (int i = 0; i < 2; ++i)
#pragma unroll
    for (int e = 0; e < 4; ++e) {
      float part = 0.f;
#pragma unroll
      for (int j = 0; j < 4; ++j) {
        int cc = wc * 64 + j * 16 + lr;
        part += fmaxf(acc[i][j][e] + b3[cc], 0.f) * wv[j];
      }
#pragma unroll
      for (int off = 8; off > 0; off >>= 1) part += __shfl_down(part, off, 16);
      if (lr == 0) zsh[wc][wr * 32 + i * 16 + lg * 4 + e] = part;
    }
  __syncthreads();
  if (tid < 64) {
    int row = bm + tid;
    if (row < NN) z[row] = zsh[0][tid] + zsh[1][tid];
  }
}

// ---------------- fill phase B: per-window scatter with LDS cursors -----------
// One block per 512-node window: cursors in LDS (ZERO global atomics), colbuk
// writes land in a 128KB window owned by THIS block only -> single-writer
// lines, flush once. Writes deg, dinv AND va = dinv*z (z ready: enc completed
// in the previous launch).
__global__ __launch_bounds__(256, 8) void fill_phaseB(
    const unsigned* __restrict__ sbuf, const int* __restrict__ gcur,
    const float* __restrict__ z, int* __restrict__ colbuk,
    int* __restrict__ deg, float* __restrict__ dinv, float* __restrict__ va)
{
  __shared__ int lcur[512];
  const int tid = threadIdx.x;
  const int b = blockIdx.x;
  for (int i = tid; i < 512; i += 256) lcur[i] = 0;
  __syncthreads();
  int cnt = min(gcur[b], SCAP);
  const unsigned* sp = sbuf + (size_t)b * SCAP;
  for (int i = tid; i < cnt; i += 256) {
    unsigned u = sp[i];
    int dloc = (int)(u >> 17);
    int s = (int)(u & 0x1FFFFu);
    int pos = atomicAdd(&lcur[dloc], 1);
    if (pos < BCAP) colbuk[(size_t)((b << 9) + dloc) * BCAP + pos] = s;
  }
  __syncthreads();
  for (int i = tid; i < 512; i += 256) {
    int node = (b << 9) + i;
    if (node < NN) {
      int dg = lcur[i];
      float di = rsqrtf((float)(dg + 1));       // +1 self-loop
      deg[node] = dg;
      dinv[node] = di;
      va[node] = di * z[node];                  // v0 (prep folded here)
    }
  }
}

// ---------------- scalar APPNP step ------------------------------------------
// Propagation commutes with the Wo projection (A acts on nodes, Wo on
// features; ReLU is encoder-only) -> all 10 steps run on per-node scalars.
// s' = 0.9*dinv*(sum_nbr v + v_self) + 0.1*z ; v' = dinv*s'. v = 400KB L2-hot.
// 16 lanes/node (avg deg ~16, max ~40 -> <=3 gather iters), width-16 reduce.
template<int LAST>
__global__ __launch_bounds__(256, 8) void appnp_sstep(
    const float* __restrict__ vin, const float* __restrict__ z,
    const float* __restrict__ dinv, const int* __restrict__ deg,
    const int* __restrict__ colbuk, float* __restrict__ vout,
    const float* __restrict__ bo, float* __restrict__ out)
{
  int tid = threadIdx.x;
  int sl = tid & 15;
  int node = blockIdx.x * 16 + (tid >> 4);
  if (node >= NN) return;
  int m = min(deg[node], BCAP);
  float val = (sl == 0) ? vin[node] : 0.f;        // self-loop term
  for (int j = sl; j < m; j += 16)
    val += vin[colbuk[(size_t)node * BCAP + j]];
#pragma unroll
  for (int off = 8; off > 0; off >>= 1) val += __shfl_down(val, off, 16);
  if (sl == 0) {
    float di = dinv[node];
    float s = 0.9f * di * val + 0.1f * z[node];
    if (LAST) out[node] = s + bo[0];
    else vout[node] = di * s;
  }
}

// ---------------- launch -----------------------------------------------------
extern "C" void kernel_launch(void* const* d_in, const int* in_sizes, int n_in,
                              void* d_out, int out_size, void* d_ws, size_t ws_size,
                              hipStream_t stream) {
  const float* x   = (const float*)d_in[0];
  const int*   ei  = (const int*)d_in[1];     // [2, NE] flat: src then dst
  const float* W1  = (const float*)d_in[2];
  const float* b1  = (const float*)d_in[3];
  const float* W2  = (const float*)d_in[4];
  const float* b2  = (const float*)d_in[5];
  const float* W3  = (const float*)d_in[6];
  const float* b3  = (const float*)d_in[7];
  const float* Wo  = (const float*)d_in[8];
  const float* bo  = (const float*)d_in[9];
  float* out = (float*)d_out;

  const int* srcv = ei;
  const int* dstv = ei + NE;

  // workspace layout
  int*      colbuk = (int*)d_ws;                              // NN*BCAP
  unsigned* sbuf   = (unsigned*)(colbuk + (size_t)NN * BCAP); // NPART*SCAP
  int*      gcur   = (int*)(sbuf + (size_t)NPART * SCAP);     // NPART
  int*      deg    = gcur + NPART;                            // NN
  float*    dinv   = (float*)(deg + NN);                      // NN
  float*    zbuf   = dinv + NN;                               // NN
  float*    va     = zbuf + NN;                               // NN
  float*    vb     = va + NN;                                 // NN
  unsigned* W1b    = (unsigned*)(vb + NN);                    // 16384 u32
  unsigned* W2b    = W1b + 16384;                             // 8192 u32
  unsigned* W3b    = W2b + 8192;                              // 8192 u32

  hipMemsetAsync(gcur, 0, NPART * 4, stream);

  // weights -> bf16 (for the fused encoder's direct B-fragment loads)
  wcvt_all<<<128, 256, 0, stream>>>(W1, W2, W3, W1b, W2b, W3b);

  // fused launch: encoder (1563 blocks) | fillA radix partition (782 blocks)
  enc_fillA<<<2346, 256, 0, stream>>>(x, (unsigned short*)W1b, b1,
                                      (unsigned short*)W2b, b2,
                                      (unsigned short*)W3b, b3, Wo, zbuf,
                                      srcv, dstv, gcur, sbuf);

  // fillB: stream -> colbuk scatter; also deg, dinv, va = dinv*z
  fill_phaseB<<<NPART, 256, 0, stream>>>(sbuf, gcur, zbuf, colbuk, deg, dinv, va);

  // 10 scalar propagation steps (pure fp32)
  int ssb = (NN + 15) / 16;
  float* cur = va; float* nxt = vb;
  for (int k = 0; k < 9; ++k) {
    appnp_sstep<0><<<ssb, 256, 0, stream>>>(cur, zbuf, dinv, deg, colbuk,
                                            nxt, nullptr, nullptr);
    float* t = cur; cur = nxt; nxt = t;
  }
  appnp_sstep<1><<<ssb, 256, 0, stream>>>(cur, zbuf, dinv, deg, colbuk,
                                          nullptr, bo, out);
}